// Round 1
// baseline (1484.100 us; speedup 1.0000x reference)
//
#include <hip/hip_runtime.h>
#include <hip/hip_bf16.h>

#define DD 128

// ---------------- CSR build ----------------

__global__ void hist_kernel(const int* __restrict__ dst, int* __restrict__ cnt, int E) {
    int e = blockIdx.x * 256 + threadIdx.x;
    if (e < E) atomicAdd(&cnt[dst[e]], 1);
}

__global__ void scanA_kernel(const int* __restrict__ cnt, int* __restrict__ row_off,
                             int* __restrict__ partials, int N) {
    __shared__ int ls[256];
    int tid = threadIdx.x;
    int i = blockIdx.x * 1024 + tid * 4;
    int c0 = (i + 0 < N) ? cnt[i + 0] : 0;
    int c1 = (i + 1 < N) ? cnt[i + 1] : 0;
    int c2 = (i + 2 < N) ? cnt[i + 2] : 0;
    int c3 = (i + 3 < N) ? cnt[i + 3] : 0;
    int tot = c0 + c1 + c2 + c3;
    ls[tid] = tot;
    __syncthreads();
    for (int off = 1; off < 256; off <<= 1) {
        int v = (tid >= off) ? ls[tid - off] : 0;
        __syncthreads();
        ls[tid] += v;
        __syncthreads();
    }
    int excl = ls[tid] - tot;
    if (tid == 255) partials[blockIdx.x] = ls[255];
    int e0 = excl, e1 = e0 + c0, e2 = e1 + c1, e3 = e2 + c2;
    if (i + 0 < N) row_off[i + 0] = e0;
    if (i + 1 < N) row_off[i + 1] = e1;
    if (i + 2 < N) row_off[i + 2] = e2;
    if (i + 3 < N) row_off[i + 3] = e3;
}

__global__ void scanB_kernel(int* partials, int nb) {
    int run = 0;
    for (int b = 0; b < nb; b++) { int t = partials[b]; partials[b] = run; run += t; }
}

__global__ void scanC_kernel(const int* __restrict__ cnt, int* __restrict__ row_off,
                             int* __restrict__ cursor, float* __restrict__ inv_deg,
                             const int* __restrict__ partials, int N) {
    int tid = threadIdx.x;
    int i = blockIdx.x * 1024 + tid * 4;
    int add = partials[blockIdx.x];
#pragma unroll
    for (int m = 0; m < 4; m++) {
        int idx = i + m;
        if (idx < N) {
            int v = row_off[idx] + add;
            row_off[idx] = v;
            cursor[idx] = v;
            int c = cnt[idx];
            inv_deg[idx] = 1.0f / (float)(c + 1);
            if (idx == N - 1) row_off[N] = v + c;
        }
    }
}

__global__ void scatter_kernel(const int* __restrict__ src, const int* __restrict__ dst,
                               int* __restrict__ cursor, int* __restrict__ csr, int E) {
    int e = blockIdx.x * 256 + threadIdx.x;
    if (e < E) {
        int d = dst[e];
        int pos = atomicAdd(&cursor[d], 1);
        csr[pos] = src[e];
    }
}

// ---------------- gather (+ fused BN-normalize+ReLU of previous layer) ----------------
// one wave per node; lane owns 2 columns (float2). NORM=0: prev is raw features.
// NORM=1: prev is pre-norm agg of previous layer; stats = (mean[128], rsqrt[128]).

template <int NORM>
__global__ __launch_bounds__(256) void gather_kernel(const float* __restrict__ prev,
                                                     const int* __restrict__ row_off,
                                                     const int* __restrict__ csr,
                                                     const float* __restrict__ stats,
                                                     float* __restrict__ sbuf, int N) {
    int node = blockIdx.x * 4 + (threadIdx.x >> 6);
    if (node >= N) return;
    int lane = threadIdx.x & 63;
    float m0 = 0.f, m1 = 0.f, r0 = 1.f, r1 = 1.f;
    if (NORM) {
        int c = 2 * lane;
        m0 = stats[c];       m1 = stats[c + 1];
        r0 = stats[128 + c]; r1 = stats[129 + c];
    }
    const float2* P = (const float2*)prev;
    int base = node * 64 + lane;
    float ax, ay;
    {
        float2 v = P[base];
        if (NORM) { ax = fmaxf((v.x - m0) * r0, 0.f); ay = fmaxf((v.y - m1) * r1, 0.f); }
        else      { ax = v.x; ay = v.y; }
    }
    int e = row_off[node], end = row_off[node + 1];
    for (; e + 4 <= end; e += 4) {
        int i0 = csr[e], i1 = csr[e + 1], i2 = csr[e + 2], i3 = csr[e + 3];
        float2 v0 = P[i0 * 64 + lane];
        float2 v1 = P[i1 * 64 + lane];
        float2 v2 = P[i2 * 64 + lane];
        float2 v3 = P[i3 * 64 + lane];
        if (NORM) {
            ax += fmaxf((v0.x - m0) * r0, 0.f) + fmaxf((v1.x - m0) * r0, 0.f)
                + fmaxf((v2.x - m0) * r0, 0.f) + fmaxf((v3.x - m0) * r0, 0.f);
            ay += fmaxf((v0.y - m1) * r1, 0.f) + fmaxf((v1.y - m1) * r1, 0.f)
                + fmaxf((v2.y - m1) * r1, 0.f) + fmaxf((v3.y - m1) * r1, 0.f);
        } else {
            ax += v0.x + v1.x + v2.x + v3.x;
            ay += v0.y + v1.y + v2.y + v3.y;
        }
    }
    for (; e < end; e++) {
        int i0 = csr[e];
        float2 v0 = P[i0 * 64 + lane];
        if (NORM) { ax += fmaxf((v0.x - m0) * r0, 0.f); ay += fmaxf((v0.y - m1) * r1, 0.f); }
        else      { ax += v0.x; ay += v0.y; }
    }
    float2 o; o.x = ax; o.y = ay;
    ((float2*)sbuf)[base] = o;
}

// ---------------- GEMM: S (in-place) = (S @ W^T) * inv_deg[row] + b[col] ----------------
// 32-row tiles. W^T and S^T staged in LDS with XOR swizzle (exactly 80KB -> 2 blocks/CU).

__global__ __launch_bounds__(256) void gemm_kernel(float* __restrict__ S, const float* __restrict__ W,
                                                   const float* __restrict__ bias,
                                                   const float* __restrict__ inv_deg, int N) {
    __shared__ float Wl[128][128];  // Wl[k][ j ^ sw(k) ] = W[j][k]
    __shared__ float Sl[128][32];   // Sl[k][ r ^ sw(k) ] = S[i0+r][k]
    int tid = threadIdx.x;
    int i0 = blockIdx.x * 32;
    int q = tid & 31;   // k-quad index (k = 4q..4q+3)
    int g = tid >> 5;   // 0..7
    int swq = (q & 7) << 2;
#pragma unroll
    for (int j = g; j < 128; j += 8) {
        float4 w = *(const float4*)&W[j * 128 + q * 4];
        int js = j ^ swq;
        Wl[q * 4 + 0][js] = w.x;
        Wl[q * 4 + 1][js] = w.y;
        Wl[q * 4 + 2][js] = w.z;
        Wl[q * 4 + 3][js] = w.w;
    }
#pragma unroll
    for (int r = g; r < 32; r += 8) {
        int row = i0 + r;
        float4 s4 = (row < N) ? *(const float4*)&S[(size_t)row * 128 + q * 4]
                              : make_float4(0.f, 0.f, 0.f, 0.f);
        int rs = r ^ swq;
        Sl[q * 4 + 0][rs] = s4.x;
        Sl[q * 4 + 1][rs] = s4.y;
        Sl[q * 4 + 2][rs] = s4.z;
        Sl[q * 4 + 3][rs] = s4.w;
    }
    __syncthreads();
    int j0 = (tid & 31) * 4;
    int r0 = (tid >> 5) * 4;
    float acc[4][4] = {};
#pragma unroll 8
    for (int k = 0; k < 128; k++) {
        int sw = ((k >> 2) & 7) << 2;
        float4 a = *(const float4*)&Sl[k][r0 ^ sw];
        float4 w = *(const float4*)&Wl[k][j0 ^ sw];
        acc[0][0] += a.x * w.x; acc[0][1] += a.x * w.y; acc[0][2] += a.x * w.z; acc[0][3] += a.x * w.w;
        acc[1][0] += a.y * w.x; acc[1][1] += a.y * w.y; acc[1][2] += a.y * w.z; acc[1][3] += a.y * w.w;
        acc[2][0] += a.z * w.x; acc[2][1] += a.z * w.y; acc[2][2] += a.z * w.z; acc[2][3] += a.z * w.w;
        acc[3][0] += a.w * w.x; acc[3][1] += a.w * w.y; acc[3][2] += a.w * w.z; acc[3][3] += a.w * w.w;
    }
    float4 bv = *(const float4*)&bias[j0];
#pragma unroll
    for (int m = 0; m < 4; m++) {
        int row = i0 + r0 + m;
        if (row < N) {
            float sc = inv_deg[row];
            float4 o;
            o.x = acc[m][0] * sc + bv.x;
            o.y = acc[m][1] * sc + bv.y;
            o.z = acc[m][2] * sc + bv.z;
            o.w = acc[m][3] * sc + bv.w;
            *(float4*)&S[(size_t)row * 128 + j0] = o;
        }
    }
}

// ---------------- BN statistics ----------------

__global__ __launch_bounds__(256) void stats_kernel(const float* __restrict__ agg,
                                                    float* __restrict__ stats, int N) {
    __shared__ float ls[256], lq[256];
    int tid = threadIdx.x;
    int c = tid & 127;
    int half = tid >> 7;
    int rbeg = blockIdx.x * 256 + half;
    int rend = min(blockIdx.x * 256 + 256, N);
    float sum = 0.f, sq = 0.f;
    for (int r = rbeg; r < rend; r += 2) {
        float v = agg[(size_t)r * 128 + c];
        sum += v; sq += v * v;
    }
    ls[tid] = sum; lq[tid] = sq;
    __syncthreads();
    if (tid < 128) {
        atomicAdd(&stats[c], ls[tid] + ls[tid + 128]);
        atomicAdd(&stats[128 + c], lq[tid] + lq[tid + 128]);
    }
}

__global__ void finalize_kernel(float* stats, float invN) {
    int c = threadIdx.x;
    float mean = stats[c] * invN;
    float var = stats[128 + c] * invN - mean * mean;
    stats[c] = mean;
    stats[128 + c] = rsqrtf(var + 1e-5f);
}

// ---------------- final normalize + relu -> d_out ----------------

__global__ __launch_bounds__(256) void outnorm_kernel(const float* __restrict__ agg,
                                                      const float* __restrict__ stats,
                                                      float* __restrict__ out, long total4) {
    long idx = (long)blockIdx.x * 256 + threadIdx.x;
    if (idx >= total4) return;
    int c0 = (int)((idx & 31) * 4);
    float4 v = ((const float4*)agg)[idx];
    float4 o;
    o.x = fmaxf((v.x - stats[c0 + 0]) * stats[128 + c0 + 0], 0.f);
    o.y = fmaxf((v.y - stats[c0 + 1]) * stats[128 + c0 + 1], 0.f);
    o.z = fmaxf((v.z - stats[c0 + 2]) * stats[128 + c0 + 2], 0.f);
    o.w = fmaxf((v.w - stats[c0 + 3]) * stats[128 + c0 + 3], 0.f);
    ((float4*)out)[idx] = o;
}

// ---------------- launch ----------------

extern "C" void kernel_launch(void* const* d_in, const int* in_sizes, int n_in,
                              void* d_out, int out_size, void* d_ws, size_t ws_size,
                              hipStream_t stream) {
    const float* x = (const float*)d_in[0];
    const int* ei = (const int*)d_in[1];
    int N = in_sizes[0] / DD;
    int E = in_sizes[1] / 2;
    const float* Wp[5];
    const float* bp[5];
    for (int l = 0; l < 5; l++) {
        Wp[l] = (const float*)d_in[2 + 2 * l];
        bp[l] = (const float*)d_in[3 + 2 * l];
    }

    char* ws = (char*)d_ws;
    size_t off = 0;
    auto alloc = [&](size_t bytes) -> char* {
        char* p = ws + off;
        off = (off + bytes + 511) & ~(size_t)511;
        return p;
    };
    int* cnt = (int*)alloc((size_t)N * 4);
    int* row_off = (int*)alloc(((size_t)N + 1) * 4);
    int* cursor = (int*)alloc((size_t)N * 4);
    int* partials = (int*)alloc(1024 * 4);
    float* inv_deg = (float*)alloc((size_t)N * 4);
    float* stats = (float*)alloc(5 * 256 * 4);
    int* csr = (int*)alloc((size_t)E * 4);
    float* bufA = (float*)alloc((size_t)N * DD * 4);
    float* bufB = (float*)alloc((size_t)N * DD * 4);
    (void)ws_size;

    const int* srcv = ei;
    const int* dstv = ei + E;

    hipMemsetAsync(cnt, 0, (size_t)N * 4, stream);
    hipMemsetAsync(stats, 0, 5 * 256 * 4, stream);

    hist_kernel<<<(E + 255) / 256, 256, 0, stream>>>(dstv, cnt, E);
    int nb = (N + 1023) / 1024;
    scanA_kernel<<<nb, 256, 0, stream>>>(cnt, row_off, partials, N);
    scanB_kernel<<<1, 1, 0, stream>>>(partials, nb);
    scanC_kernel<<<nb, 256, 0, stream>>>(cnt, row_off, cursor, inv_deg, partials, N);
    scatter_kernel<<<(E + 255) / 256, 256, 0, stream>>>(srcv, dstv, cursor, csr, E);

    float invN = 1.0f / (float)N;
    int gblocks = (N + 3) / 4;
    int mblocks = (N + 31) / 32;
    int sblocks = (N + 255) / 256;

    float* aggbuf[5] = {bufA, bufB, bufA, bufB, bufA};
    for (int l = 0; l < 5; l++) {
        float* sb = aggbuf[l];
        if (l == 0) {
            gather_kernel<0><<<gblocks, 256, 0, stream>>>(x, row_off, csr, nullptr, sb, N);
        } else {
            gather_kernel<1><<<gblocks, 256, 0, stream>>>(aggbuf[l - 1], row_off, csr,
                                                          stats + (l - 1) * 256, sb, N);
        }
        gemm_kernel<<<mblocks, 256, 0, stream>>>(sb, Wp[l], bp[l], inv_deg, N);
        stats_kernel<<<sblocks, 256, 0, stream>>>(sb, stats + l * 256, N);
        finalize_kernel<<<1, 128, 0, stream>>>(stats + l * 256, invN);
    }

    long total4 = (long)N * (DD / 4);
    outnorm_kernel<<<(int)((total4 + 255) / 256), 256, 0, stream>>>(aggbuf[4], stats + 4 * 256,
                                                                    (float*)d_out, total4);
}

// Round 2
// 1239.732 us; speedup vs baseline: 1.1971x; 1.1971x over previous
//
#include <hip/hip_runtime.h>
#include <hip/hip_bf16.h>

#define DD 128
#define NPART 8

typedef __bf16 bf16x8 __attribute__((ext_vector_type(8)));
typedef float f32x4 __attribute__((ext_vector_type(4)));

// ---------------- CSR build ----------------

// XCD-partitioned histogram: block b handles dst range [(b%8)*psize, ...).
// blockIdx%8 round-robins across XCDs, so cnt lines are written from one XCD
// only and partial-line merges happen in that XCD's coherent L2.
__global__ __launch_bounds__(256) void hist_kernel(const int* __restrict__ dst,
                                                   int* __restrict__ cnt, int E, int psize) {
    int part = blockIdx.x & (NPART - 1);
    int lo = part * psize, hi = lo + psize;
    int stride = (gridDim.x >> 3) * 256;
    for (int e = (blockIdx.x >> 3) * 256 + threadIdx.x; e < E; e += stride) {
        int d = dst[e];
        if (d >= lo && d < hi) atomicAdd(&cnt[d], 1);
    }
}

__global__ void scanA_kernel(const int* __restrict__ cnt, int* __restrict__ row_off,
                             int* __restrict__ partials, int N) {
    __shared__ int ls[256];
    int tid = threadIdx.x;
    int i = blockIdx.x * 1024 + tid * 4;
    int c0 = (i + 0 < N) ? cnt[i + 0] : 0;
    int c1 = (i + 1 < N) ? cnt[i + 1] : 0;
    int c2 = (i + 2 < N) ? cnt[i + 2] : 0;
    int c3 = (i + 3 < N) ? cnt[i + 3] : 0;
    int tot = c0 + c1 + c2 + c3;
    ls[tid] = tot;
    __syncthreads();
    for (int off = 1; off < 256; off <<= 1) {
        int v = (tid >= off) ? ls[tid - off] : 0;
        __syncthreads();
        ls[tid] += v;
        __syncthreads();
    }
    int excl = ls[tid] - tot;
    if (tid == 255) partials[blockIdx.x] = ls[255];
    int e0 = excl, e1 = e0 + c0, e2 = e1 + c1, e3 = e2 + c2;
    if (i + 0 < N) row_off[i + 0] = e0;
    if (i + 1 < N) row_off[i + 1] = e1;
    if (i + 2 < N) row_off[i + 2] = e2;
    if (i + 3 < N) row_off[i + 3] = e3;
}

__global__ void scanB_kernel(int* partials, int nb) {
    int run = 0;
    for (int b = 0; b < nb; b++) { int t = partials[b]; partials[b] = run; run += t; }
}

__global__ void scanC_kernel(const int* __restrict__ cnt, int* __restrict__ row_off,
                             int* __restrict__ cursor, float* __restrict__ inv_deg,
                             const int* __restrict__ partials, int N) {
    int tid = threadIdx.x;
    int i = blockIdx.x * 1024 + tid * 4;
    int add = partials[blockIdx.x];
#pragma unroll
    for (int m = 0; m < 4; m++) {
        int idx = i + m;
        if (idx < N) {
            int v = row_off[idx] + add;
            row_off[idx] = v;
            cursor[idx] = v;
            int c = cnt[idx];
            inv_deg[idx] = 1.0f / (float)(c + 1);
            if (idx == N - 1) row_off[N] = v + c;
        }
    }
}

// XCD-partitioned scatter: csr region for a dst-range is contiguous, so all
// writes from part p land in one XCD-local slice -> full-line merges in L2.
__global__ __launch_bounds__(256) void scatter_kernel(const int* __restrict__ src,
                                                      const int* __restrict__ dst,
                                                      int* __restrict__ cursor,
                                                      int* __restrict__ csr, int E, int psize) {
    int part = blockIdx.x & (NPART - 1);
    int lo = part * psize, hi = lo + psize;
    int stride = (gridDim.x >> 3) * 256;
    for (int e = (blockIdx.x >> 3) * 256 + threadIdx.x; e < E; e += stride) {
        int d = dst[e];
        if (d >= lo && d < hi) {
            int pos = atomicAdd(&cursor[d], 1);
            csr[pos] = src[e];
        }
    }
}

// ---------------- gather (+ fused BN-normalize+ReLU of previous layer) ----------------

template <int NORM>
__global__ __launch_bounds__(256) void gather_kernel(const float* __restrict__ prev,
                                                     const int* __restrict__ row_off,
                                                     const int* __restrict__ csr,
                                                     const float* __restrict__ stats,
                                                     float* __restrict__ sbuf, int N) {
    int node = blockIdx.x * 4 + (threadIdx.x >> 6);
    if (node >= N) return;
    int lane = threadIdx.x & 63;
    float m0 = 0.f, m1 = 0.f, r0 = 1.f, r1 = 1.f;
    if (NORM) {
        int c = 2 * lane;
        m0 = stats[c];       m1 = stats[c + 1];
        r0 = stats[128 + c]; r1 = stats[129 + c];
    }
    const float2* P = (const float2*)prev;
    int base = node * 64 + lane;
    float ax, ay;
    {
        float2 v = P[base];
        if (NORM) { ax = fmaxf((v.x - m0) * r0, 0.f); ay = fmaxf((v.y - m1) * r1, 0.f); }
        else      { ax = v.x; ay = v.y; }
    }
    int e = row_off[node], end = row_off[node + 1];
    for (; e + 4 <= end; e += 4) {
        int i0 = csr[e], i1 = csr[e + 1], i2 = csr[e + 2], i3 = csr[e + 3];
        float2 v0 = P[i0 * 64 + lane];
        float2 v1 = P[i1 * 64 + lane];
        float2 v2 = P[i2 * 64 + lane];
        float2 v3 = P[i3 * 64 + lane];
        if (NORM) {
            ax += fmaxf((v0.x - m0) * r0, 0.f) + fmaxf((v1.x - m0) * r0, 0.f)
                + fmaxf((v2.x - m0) * r0, 0.f) + fmaxf((v3.x - m0) * r0, 0.f);
            ay += fmaxf((v0.y - m1) * r1, 0.f) + fmaxf((v1.y - m1) * r1, 0.f)
                + fmaxf((v2.y - m1) * r1, 0.f) + fmaxf((v3.y - m1) * r1, 0.f);
        } else {
            ax += v0.x + v1.x + v2.x + v3.x;
            ay += v0.y + v1.y + v2.y + v3.y;
        }
    }
    for (; e < end; e++) {
        int i0 = csr[e];
        float2 v0 = P[i0 * 64 + lane];
        if (NORM) { ax += fmaxf((v0.x - m0) * r0, 0.f); ay += fmaxf((v0.y - m1) * r1, 0.f); }
        else      { ax += v0.x; ay += v0.y; }
    }
    float2 o; o.x = ax; o.y = ay;
    ((float2*)sbuf)[base] = o;
}

// ---------------- W split into bf16 hi/lo planes ----------------

__global__ void wsplit_kernel(const float* __restrict__ W0, const float* __restrict__ W1,
                              const float* __restrict__ W2, const float* __restrict__ W3,
                              const float* __restrict__ W4, unsigned short* __restrict__ whl) {
    int idx = blockIdx.x * 256 + threadIdx.x;  // < 5*16384
    int l = idx >> 14, r = idx & 16383;
    const float* W = (l == 0) ? W0 : (l == 1) ? W1 : (l == 2) ? W2 : (l == 3) ? W3 : W4;
    float x = W[r];
    unsigned u = __float_as_uint(x);
    unsigned short h = (unsigned short)(u >> 16);
    float hf = __uint_as_float(u & 0xffff0000u);
    float lo = x - hf;  // exact
    unsigned short lw = (unsigned short)(__float_as_uint(lo) >> 16);
    whl[l * 32768 + r] = h;
    whl[l * 32768 + 16384 + r] = lw;
}

// ---------------- MFMA GEMM: S (in-place) = (S @ W^T) * inv_deg[row] + b[col] ----------
// split-bf16 (3-term) for fp32-equivalent accuracy. 128-row tile, 4 waves.
// Fused BN-stat accumulation (sum, sumsq per column) via atomics.

__global__ __launch_bounds__(256) void mgemm_kernel(float* __restrict__ S,
                                                    const unsigned short* __restrict__ Whl,
                                                    const float* __restrict__ bias,
                                                    const float* __restrict__ inv_deg,
                                                    float* __restrict__ stats, int N) {
    __shared__ unsigned short ShL[128 * 128];  // hi plane, XOR-swizzled 16B chunks
    __shared__ unsigned short SlL[128 * 128];  // lo plane
    const int t = threadIdx.x;
    const int i0 = blockIdx.x * 128;

    // ---- stage + split S tile (zeros for OOB rows) ----
#pragma unroll
    for (int b = 0; b < 16; b++) {
        int f = t + 256 * b;
        int r = f >> 5, k4 = f & 31;
        int row = i0 + r;
        float4 v = (row < N) ? *(const float4*)&S[(size_t)row * 128 + k4 * 4]
                             : make_float4(0.f, 0.f, 0.f, 0.f);
        int k8 = k4 >> 1;
        int base = r * 128 + ((k8 ^ (r & 7)) * 8) + (k4 & 1) * 4;
        ushort4 h, lw;
        {
            unsigned u = __float_as_uint(v.x); h.x = (unsigned short)(u >> 16);
            float d = v.x - __uint_as_float(u & 0xffff0000u); lw.x = (unsigned short)(__float_as_uint(d) >> 16);
            u = __float_as_uint(v.y); h.y = (unsigned short)(u >> 16);
            d = v.y - __uint_as_float(u & 0xffff0000u); lw.y = (unsigned short)(__float_as_uint(d) >> 16);
            u = __float_as_uint(v.z); h.z = (unsigned short)(u >> 16);
            d = v.z - __uint_as_float(u & 0xffff0000u); lw.z = (unsigned short)(__float_as_uint(d) >> 16);
            u = __float_as_uint(v.w); h.w = (unsigned short)(u >> 16);
            d = v.w - __uint_as_float(u & 0xffff0000u); lw.w = (unsigned short)(__float_as_uint(d) >> 16);
        }
        *(ushort4*)(ShL + base) = h;
        *(ushort4*)(SlL + base) = lw;
    }
    __syncthreads();

    // ---- MFMA main loop ----
    const int w = t >> 6, l = t & 63;
    const int ll = l & 15, lh = l >> 4;
    const unsigned short* Wh = Whl;
    const unsigned short* Wl2 = Whl + 16384;
    f32x4 acc[2][8];
#pragma unroll
    for (int st = 0; st < 2; st++)
#pragma unroll
        for (int jt = 0; jt < 8; jt++) acc[st][jt] = (f32x4){0.f, 0.f, 0.f, 0.f};

    const int r0 = w * 32 + ll;
    const int r1 = r0 + 16;
#pragma unroll
    for (int ks = 0; ks < 4; ks++) {
        int k8 = ks * 4 + lh;
        int ia0 = r0 * 128 + ((k8 ^ (r0 & 7)) * 8);
        int ia1 = r1 * 128 + ((k8 ^ (r1 & 7)) * 8);
        bf16x8 ah0 = *(const bf16x8*)(ShL + ia0);
        bf16x8 al0 = *(const bf16x8*)(SlL + ia0);
        bf16x8 ah1 = *(const bf16x8*)(ShL + ia1);
        bf16x8 al1 = *(const bf16x8*)(SlL + ia1);
        int wk = ks * 32 + lh * 8;
#pragma unroll
        for (int jt = 0; jt < 8; jt++) {
            int wrow = jt * 16 + ll;
            bf16x8 bh = *(const bf16x8*)(Wh + wrow * 128 + wk);
            bf16x8 bl = *(const bf16x8*)(Wl2 + wrow * 128 + wk);
            acc[0][jt] = __builtin_amdgcn_mfma_f32_16x16x32_bf16(ah0, bh, acc[0][jt], 0, 0, 0);
            acc[1][jt] = __builtin_amdgcn_mfma_f32_16x16x32_bf16(ah1, bh, acc[1][jt], 0, 0, 0);
            acc[0][jt] = __builtin_amdgcn_mfma_f32_16x16x32_bf16(al0, bh, acc[0][jt], 0, 0, 0);
            acc[1][jt] = __builtin_amdgcn_mfma_f32_16x16x32_bf16(al1, bh, acc[1][jt], 0, 0, 0);
            acc[0][jt] = __builtin_amdgcn_mfma_f32_16x16x32_bf16(ah0, bl, acc[0][jt], 0, 0, 0);
            acc[1][jt] = __builtin_amdgcn_mfma_f32_16x16x32_bf16(ah1, bl, acc[1][jt], 0, 0, 0);
        }
    }

    // ---- epilogue: scale + bias, store, accumulate column stats ----
    float bj[8];
#pragma unroll
    for (int jt = 0; jt < 8; jt++) bj[jt] = bias[jt * 16 + ll];
    float cs[8], cq[8];
#pragma unroll
    for (int jt = 0; jt < 8; jt++) { cs[jt] = 0.f; cq[jt] = 0.f; }
#pragma unroll
    for (int st = 0; st < 2; st++) {
#pragma unroll
        for (int reg = 0; reg < 4; reg++) {
            int row = i0 + w * 32 + st * 16 + lh * 4 + reg;
            bool valid = row < N;
            float sc = valid ? inv_deg[row] : 0.f;
#pragma unroll
            for (int jt = 0; jt < 8; jt++) {
                float o = acc[st][jt][reg] * sc + bj[jt];
                if (valid) {
                    S[(size_t)row * 128 + jt * 16 + ll] = o;
                    cs[jt] += o;
                    cq[jt] += o * o;
                }
            }
        }
    }
#pragma unroll
    for (int jt = 0; jt < 8; jt++) {
        cs[jt] += __shfl_xor(cs[jt], 16);
        cs[jt] += __shfl_xor(cs[jt], 32);
        cq[jt] += __shfl_xor(cq[jt], 16);
        cq[jt] += __shfl_xor(cq[jt], 32);
    }
    __syncthreads();  // all LDS reads done; reuse ShL for stats reduction
    float* sred = (float*)ShL;  // [4 waves][2 stats][128 cols]
    if (l < 16) {
#pragma unroll
        for (int jt = 0; jt < 8; jt++) {
            sred[w * 256 + jt * 16 + l] = cs[jt];
            sred[w * 256 + 128 + jt * 16 + l] = cq[jt];
        }
    }
    __syncthreads();
    {
        int col = t & 127, s = t >> 7;
        float v = sred[0 * 256 + s * 128 + col] + sred[1 * 256 + s * 128 + col]
                + sred[2 * 256 + s * 128 + col] + sred[3 * 256 + s * 128 + col];
        atomicAdd(&stats[s * 128 + col], v);
    }
}

// ---------------- BN finalize ----------------

__global__ void finalize_kernel(float* stats, float invN) {
    int c = threadIdx.x;
    float mean = stats[c] * invN;
    float var = stats[128 + c] * invN - mean * mean;
    stats[c] = mean;
    stats[128 + c] = rsqrtf(var + 1e-5f);
}

// ---------------- final normalize + relu -> d_out ----------------

__global__ __launch_bounds__(256) void outnorm_kernel(const float* __restrict__ agg,
                                                      const float* __restrict__ stats,
                                                      float* __restrict__ out, long total4) {
    long idx = (long)blockIdx.x * 256 + threadIdx.x;
    if (idx >= total4) return;
    int c0 = (int)((idx & 31) * 4);
    float4 v = ((const float4*)agg)[idx];
    float4 o;
    o.x = fmaxf((v.x - stats[c0 + 0]) * stats[128 + c0 + 0], 0.f);
    o.y = fmaxf((v.y - stats[c0 + 1]) * stats[128 + c0 + 1], 0.f);
    o.z = fmaxf((v.z - stats[c0 + 2]) * stats[128 + c0 + 2], 0.f);
    o.w = fmaxf((v.w - stats[c0 + 3]) * stats[128 + c0 + 3], 0.f);
    ((float4*)out)[idx] = o;
}

// ---------------- launch ----------------

extern "C" void kernel_launch(void* const* d_in, const int* in_sizes, int n_in,
                              void* d_out, int out_size, void* d_ws, size_t ws_size,
                              hipStream_t stream) {
    const float* x = (const float*)d_in[0];
    const int* ei = (const int*)d_in[1];
    int N = in_sizes[0] / DD;
    int E = in_sizes[1] / 2;
    const float* Wp[5];
    const float* bp[5];
    for (int l = 0; l < 5; l++) {
        Wp[l] = (const float*)d_in[2 + 2 * l];
        bp[l] = (const float*)d_in[3 + 2 * l];
    }

    char* ws = (char*)d_ws;
    size_t off = 0;
    auto alloc = [&](size_t bytes) -> char* {
        char* p = ws + off;
        off = (off + bytes + 511) & ~(size_t)511;
        return p;
    };
    int* cnt = (int*)alloc((size_t)N * 4);
    int* row_off = (int*)alloc(((size_t)N + 1) * 4);
    int* cursor = (int*)alloc((size_t)N * 4);
    int* partials = (int*)alloc(1024 * 4);
    float* inv_deg = (float*)alloc((size_t)N * 4);
    float* stats = (float*)alloc(5 * 256 * 4);
    unsigned short* whl = (unsigned short*)alloc(5 * 32768 * 2);
    int* csr = (int*)alloc((size_t)E * 4);
    float* bufA = (float*)alloc((size_t)N * DD * 4);
    float* bufB = (float*)alloc((size_t)N * DD * 4);
    (void)ws_size;

    const int* srcv = ei;
    const int* dstv = ei + E;

    hipMemsetAsync(cnt, 0, (size_t)N * 4, stream);
    hipMemsetAsync(stats, 0, 5 * 256 * 4, stream);

    wsplit_kernel<<<5 * 16384 / 256, 256, 0, stream>>>(Wp[0], Wp[1], Wp[2], Wp[3], Wp[4], whl);

    int psize = (N + NPART - 1) / NPART;
    hist_kernel<<<NPART * 128, 256, 0, stream>>>(dstv, cnt, E, psize);
    int nb = (N + 1023) / 1024;
    scanA_kernel<<<nb, 256, 0, stream>>>(cnt, row_off, partials, N);
    scanB_kernel<<<1, 1, 0, stream>>>(partials, nb);
    scanC_kernel<<<nb, 256, 0, stream>>>(cnt, row_off, cursor, inv_deg, partials, N);
    scatter_kernel<<<NPART * 128, 256, 0, stream>>>(srcv, dstv, cursor, csr, E, psize);

    float invN = 1.0f / (float)N;
    int gblocks = (N + 3) / 4;
    int mblocks = (N + 127) / 128;

    float* aggbuf[5] = {bufA, bufB, bufA, bufB, bufA};
    for (int l = 0; l < 5; l++) {
        float* sb = aggbuf[l];
        if (l == 0) {
            gather_kernel<0><<<gblocks, 256, 0, stream>>>(x, row_off, csr, nullptr, sb, N);
        } else {
            gather_kernel<1><<<gblocks, 256, 0, stream>>>(aggbuf[l - 1], row_off, csr,
                                                          stats + (l - 1) * 256, sb, N);
        }
        mgemm_kernel<<<mblocks, 256, 0, stream>>>(sb, whl + l * 32768, bp[l], inv_deg,
                                                  stats + l * 256, N);
        finalize_kernel<<<1, 128, 0, stream>>>(stats + l * 256, invN);
    }

    long total4 = (long)N * (DD / 4);
    outnorm_kernel<<<(int)((total4 + 255) / 256), 256, 0, stream>>>(aggbuf[4], stats + 4 * 256,
                                                                    (float*)d_out, total4);
}

// Round 3
// 1014.909 us; speedup vs baseline: 1.4623x; 1.2215x over previous
//
#include <hip/hip_runtime.h>
#include <hip/hip_bf16.h>

#define DD 128
#define NPART 8

typedef __bf16 bf16x8 __attribute__((ext_vector_type(8)));
typedef float f32x4 __attribute__((ext_vector_type(4)));

__device__ inline unsigned short f2bf_rne(float f) {
    unsigned u = __float_as_uint(f);
    u += 0x7fff + ((u >> 16) & 1);
    return (unsigned short)(u >> 16);
}

// ---------------- CSR build ----------------

__global__ __launch_bounds__(256) void hist_kernel(const int* __restrict__ dst,
                                                   int* __restrict__ cnt, int E, int psize) {
    int part = blockIdx.x & (NPART - 1);
    int lo = part * psize, hi = lo + psize;
    int stride = (gridDim.x >> 3) * 256;
    for (int e = (blockIdx.x >> 3) * 256 + threadIdx.x; e < E; e += stride) {
        int d = dst[e];
        if (d >= lo && d < hi) atomicAdd(&cnt[d], 1);
    }
}

__global__ void scanA_kernel(const int* __restrict__ cnt, int* __restrict__ row_off,
                             int* __restrict__ partials, int N) {
    __shared__ int ls[256];
    int tid = threadIdx.x;
    int i = blockIdx.x * 1024 + tid * 4;
    int c0 = (i + 0 < N) ? cnt[i + 0] : 0;
    int c1 = (i + 1 < N) ? cnt[i + 1] : 0;
    int c2 = (i + 2 < N) ? cnt[i + 2] : 0;
    int c3 = (i + 3 < N) ? cnt[i + 3] : 0;
    int tot = c0 + c1 + c2 + c3;
    ls[tid] = tot;
    __syncthreads();
    for (int off = 1; off < 256; off <<= 1) {
        int v = (tid >= off) ? ls[tid - off] : 0;
        __syncthreads();
        ls[tid] += v;
        __syncthreads();
    }
    int excl = ls[tid] - tot;
    if (tid == 255) partials[blockIdx.x] = ls[255];
    int e0 = excl, e1 = e0 + c0, e2 = e1 + c1, e3 = e2 + c2;
    if (i + 0 < N) row_off[i + 0] = e0;
    if (i + 1 < N) row_off[i + 1] = e1;
    if (i + 2 < N) row_off[i + 2] = e2;
    if (i + 3 < N) row_off[i + 3] = e3;
}

// parallel single-block exclusive scan over block partials (nb <= a few thousand)
__global__ __launch_bounds__(256) void scanB_kernel(int* partials, int nb) {
    __shared__ int ls[256];
    int tid = threadIdx.x;
    int base = 0;
    for (int c = 0; c < nb; c += 256) {
        int v = (c + tid < nb) ? partials[c + tid] : 0;
        ls[tid] = v;
        __syncthreads();
        for (int off = 1; off < 256; off <<= 1) {
            int t = (tid >= off) ? ls[tid - off] : 0;
            __syncthreads();
            ls[tid] += t;
            __syncthreads();
        }
        if (c + tid < nb) partials[c + tid] = ls[tid] - v + base;
        int tot = ls[255];
        __syncthreads();
        base += tot;
    }
}

__global__ void scanC_kernel(const int* __restrict__ cnt, int* __restrict__ row_off,
                             int* __restrict__ cursor, float* __restrict__ inv_deg,
                             const int* __restrict__ partials, int N) {
    int tid = threadIdx.x;
    int i = blockIdx.x * 1024 + tid * 4;
    int add = partials[blockIdx.x];
#pragma unroll
    for (int m = 0; m < 4; m++) {
        int idx = i + m;
        if (idx < N) {
            int v = row_off[idx] + add;
            row_off[idx] = v;
            cursor[idx] = v;
            int c = cnt[idx];
            inv_deg[idx] = 1.0f / (float)(c + 1);
            if (idx == N - 1) row_off[N] = v + c;
        }
    }
}

__global__ __launch_bounds__(256) void scatter_kernel(const int* __restrict__ src,
                                                      const int* __restrict__ dst,
                                                      int* __restrict__ cursor,
                                                      int* __restrict__ csr, int E, int psize) {
    int part = blockIdx.x & (NPART - 1);
    int lo = part * psize, hi = lo + psize;
    int stride = (gridDim.x >> 3) * 256;
    for (int e = (blockIdx.x >> 3) * 256 + threadIdx.x; e < E; e += stride) {
        int d = dst[e];
        if (d >= lo && d < hi) {
            int pos = atomicAdd(&cursor[d], 1);
            csr[pos] = src[e];
        }
    }
}

// ---------------- x -> bf16 ----------------

__global__ __launch_bounds__(256) void tobf16_kernel(const float* __restrict__ x,
                                                     unsigned short* __restrict__ h, long total4) {
    long idx = (long)blockIdx.x * 256 + threadIdx.x;
    if (idx >= total4) return;
    float4 v = ((const float4*)x)[idx];
    ushort4 o;
    o.x = f2bf_rne(v.x); o.y = f2bf_rne(v.y); o.z = f2bf_rne(v.z); o.w = f2bf_rne(v.w);
    ((ushort4*)h)[idx] = o;
}

// ---------------- gather (bf16 in, fp32 out, fused prev-layer BN+ReLU) ----------------
// one wave per node; lane owns 2 columns (one packed uint = 2 bf16).

template <int NORM>
__global__ __launch_bounds__(256) void gather_kernel(const unsigned int* __restrict__ prev,
                                                     const int* __restrict__ row_off,
                                                     const int* __restrict__ csr,
                                                     const float* __restrict__ stats,
                                                     float* __restrict__ sbuf, int N) {
    int node = blockIdx.x * 4 + (threadIdx.x >> 6);
    if (node >= N) return;
    int lane = threadIdx.x & 63;
    float m0 = 0.f, m1 = 0.f, r0 = 1.f, r1 = 1.f;
    if (NORM) {
        int c = 2 * lane;
        m0 = stats[c];       m1 = stats[c + 1];
        r0 = stats[128 + c]; r1 = stats[129 + c];
    }
    int base = node * 64 + lane;
    float ax, ay;
    {
        unsigned u = prev[base];
        float vx = __uint_as_float(u << 16);
        float vy = __uint_as_float(u & 0xffff0000u);
        if (NORM) { ax = fmaxf((vx - m0) * r0, 0.f); ay = fmaxf((vy - m1) * r1, 0.f); }
        else      { ax = vx; ay = vy; }
    }
    int e = row_off[node], end = row_off[node + 1];
    for (; e + 4 <= end; e += 4) {
        int i0 = csr[e], i1 = csr[e + 1], i2 = csr[e + 2], i3 = csr[e + 3];
        unsigned u0 = prev[i0 * 64 + lane];
        unsigned u1 = prev[i1 * 64 + lane];
        unsigned u2 = prev[i2 * 64 + lane];
        unsigned u3 = prev[i3 * 64 + lane];
        float x0 = __uint_as_float(u0 << 16), y0 = __uint_as_float(u0 & 0xffff0000u);
        float x1 = __uint_as_float(u1 << 16), y1 = __uint_as_float(u1 & 0xffff0000u);
        float x2 = __uint_as_float(u2 << 16), y2 = __uint_as_float(u2 & 0xffff0000u);
        float x3 = __uint_as_float(u3 << 16), y3 = __uint_as_float(u3 & 0xffff0000u);
        if (NORM) {
            ax += fmaxf((x0 - m0) * r0, 0.f) + fmaxf((x1 - m0) * r0, 0.f)
                + fmaxf((x2 - m0) * r0, 0.f) + fmaxf((x3 - m0) * r0, 0.f);
            ay += fmaxf((y0 - m1) * r1, 0.f) + fmaxf((y1 - m1) * r1, 0.f)
                + fmaxf((y2 - m1) * r1, 0.f) + fmaxf((y3 - m1) * r1, 0.f);
        } else {
            ax += x0 + x1 + x2 + x3;
            ay += y0 + y1 + y2 + y3;
        }
    }
    for (; e < end; e++) {
        unsigned u0 = prev[csr[e] * 64 + lane];
        float x0 = __uint_as_float(u0 << 16), y0 = __uint_as_float(u0 & 0xffff0000u);
        if (NORM) { ax += fmaxf((x0 - m0) * r0, 0.f); ay += fmaxf((y0 - m1) * r1, 0.f); }
        else      { ax += x0; ay += y0; }
    }
    float2 o; o.x = ax; o.y = ay;
    ((float2*)sbuf)[base] = o;
}

// ---------------- W split into bf16 hi/lo planes ----------------

__global__ void wsplit_kernel(const float* __restrict__ W0, const float* __restrict__ W1,
                              const float* __restrict__ W2, const float* __restrict__ W3,
                              const float* __restrict__ W4, unsigned short* __restrict__ whl) {
    int idx = blockIdx.x * 256 + threadIdx.x;  // < 5*16384
    int l = idx >> 14, r = idx & 16383;
    const float* W = (l == 0) ? W0 : (l == 1) ? W1 : (l == 2) ? W2 : (l == 3) ? W3 : W4;
    float x = W[r];
    unsigned u = __float_as_uint(x);
    unsigned short h = (unsigned short)(u >> 16);
    float hf = __uint_as_float(u & 0xffff0000u);
    float lo = x - hf;  // exact
    unsigned short lw = (unsigned short)(__float_as_uint(lo) >> 16);
    whl[l * 32768 + r] = h;
    whl[l * 32768 + 16384 + r] = lw;
}

// ---------------- MFMA GEMM ----------------
// out = (Sin @ W^T) * inv_deg[row] + b[col]; split-bf16 3-term; fused BN stats.
// LAST=0: write bf16 to outh.  LAST=1: write fp32 in-place to Sio (== Sin).

template <int LAST>
__global__ __launch_bounds__(256) void mgemm_kernel(const float* __restrict__ Sin,
                                                    unsigned short* __restrict__ outh,
                                                    float* __restrict__ Sio,
                                                    const unsigned short* __restrict__ Whl,
                                                    const float* __restrict__ bias,
                                                    const float* __restrict__ inv_deg,
                                                    float* __restrict__ stats, int N) {
    __shared__ unsigned short ShL[128 * 128];  // hi plane, XOR-swizzled 16B chunks
    __shared__ unsigned short SlL[128 * 128];  // lo plane
    const int t = threadIdx.x;
    const int i0 = blockIdx.x * 128;

#pragma unroll
    for (int b = 0; b < 16; b++) {
        int f = t + 256 * b;
        int r = f >> 5, k4 = f & 31;
        int row = i0 + r;
        float4 v = (row < N) ? *(const float4*)&Sin[(size_t)row * 128 + k4 * 4]
                             : make_float4(0.f, 0.f, 0.f, 0.f);
        int k8 = k4 >> 1;
        int base = r * 128 + ((k8 ^ (r & 7)) * 8) + (k4 & 1) * 4;
        ushort4 h, lw;
        {
            unsigned u = __float_as_uint(v.x); h.x = (unsigned short)(u >> 16);
            float d = v.x - __uint_as_float(u & 0xffff0000u); lw.x = (unsigned short)(__float_as_uint(d) >> 16);
            u = __float_as_uint(v.y); h.y = (unsigned short)(u >> 16);
            d = v.y - __uint_as_float(u & 0xffff0000u); lw.y = (unsigned short)(__float_as_uint(d) >> 16);
            u = __float_as_uint(v.z); h.z = (unsigned short)(u >> 16);
            d = v.z - __uint_as_float(u & 0xffff0000u); lw.z = (unsigned short)(__float_as_uint(d) >> 16);
            u = __float_as_uint(v.w); h.w = (unsigned short)(u >> 16);
            d = v.w - __uint_as_float(u & 0xffff0000u); lw.w = (unsigned short)(__float_as_uint(d) >> 16);
        }
        *(ushort4*)(ShL + base) = h;
        *(ushort4*)(SlL + base) = lw;
    }
    __syncthreads();

    const int w = t >> 6, l = t & 63;
    const int ll = l & 15, lh = l >> 4;
    const unsigned short* Wh = Whl;
    const unsigned short* Wl2 = Whl + 16384;
    f32x4 acc[2][8];
#pragma unroll
    for (int st = 0; st < 2; st++)
#pragma unroll
        for (int jt = 0; jt < 8; jt++) acc[st][jt] = (f32x4){0.f, 0.f, 0.f, 0.f};

    const int r0 = w * 32 + ll;
    const int r1 = r0 + 16;
#pragma unroll
    for (int ks = 0; ks < 4; ks++) {
        int k8 = ks * 4 + lh;
        int ia0 = r0 * 128 + ((k8 ^ (r0 & 7)) * 8);
        int ia1 = r1 * 128 + ((k8 ^ (r1 & 7)) * 8);
        bf16x8 ah0 = *(const bf16x8*)(ShL + ia0);
        bf16x8 al0 = *(const bf16x8*)(SlL + ia0);
        bf16x8 ah1 = *(const bf16x8*)(ShL + ia1);
        bf16x8 al1 = *(const bf16x8*)(SlL + ia1);
        int wk = ks * 32 + lh * 8;
#pragma unroll
        for (int jt = 0; jt < 8; jt++) {
            int wrow = jt * 16 + ll;
            bf16x8 bh = *(const bf16x8*)(Wh + wrow * 128 + wk);
            bf16x8 bl = *(const bf16x8*)(Wl2 + wrow * 128 + wk);
            acc[0][jt] = __builtin_amdgcn_mfma_f32_16x16x32_bf16(ah0, bh, acc[0][jt], 0, 0, 0);
            acc[1][jt] = __builtin_amdgcn_mfma_f32_16x16x32_bf16(ah1, bh, acc[1][jt], 0, 0, 0);
            acc[0][jt] = __builtin_amdgcn_mfma_f32_16x16x32_bf16(al0, bh, acc[0][jt], 0, 0, 0);
            acc[1][jt] = __builtin_amdgcn_mfma_f32_16x16x32_bf16(al1, bh, acc[1][jt], 0, 0, 0);
            acc[0][jt] = __builtin_amdgcn_mfma_f32_16x16x32_bf16(ah0, bl, acc[0][jt], 0, 0, 0);
            acc[1][jt] = __builtin_amdgcn_mfma_f32_16x16x32_bf16(ah1, bl, acc[1][jt], 0, 0, 0);
        }
    }

    float bj[8];
#pragma unroll
    for (int jt = 0; jt < 8; jt++) bj[jt] = bias[jt * 16 + ll];
    float cs[8], cq[8];
#pragma unroll
    for (int jt = 0; jt < 8; jt++) { cs[jt] = 0.f; cq[jt] = 0.f; }
#pragma unroll
    for (int st = 0; st < 2; st++) {
#pragma unroll
        for (int reg = 0; reg < 4; reg++) {
            int row = i0 + w * 32 + st * 16 + lh * 4 + reg;
            bool valid = row < N;
            float sc = valid ? inv_deg[row] : 0.f;
#pragma unroll
            for (int jt = 0; jt < 8; jt++) {
                float o = acc[st][jt][reg] * sc + bj[jt];
                if (valid) {
                    if (LAST) Sio[(size_t)row * 128 + jt * 16 + ll] = o;
                    else      outh[(size_t)row * 128 + jt * 16 + ll] = f2bf_rne(o);
                    cs[jt] += o;
                    cq[jt] += o * o;
                }
            }
        }
    }
#pragma unroll
    for (int jt = 0; jt < 8; jt++) {
        cs[jt] += __shfl_xor(cs[jt], 16);
        cs[jt] += __shfl_xor(cs[jt], 32);
        cq[jt] += __shfl_xor(cq[jt], 16);
        cq[jt] += __shfl_xor(cq[jt], 32);
    }
    __syncthreads();  // all LDS reads done; reuse ShL for stats reduction
    float* sred = (float*)ShL;  // [4 waves][2 stats][128 cols]
    if (l < 16) {
#pragma unroll
        for (int jt = 0; jt < 8; jt++) {
            sred[w * 256 + jt * 16 + l] = cs[jt];
            sred[w * 256 + 128 + jt * 16 + l] = cq[jt];
        }
    }
    __syncthreads();
    {
        int col = t & 127, s = t >> 7;
        float v = sred[0 * 256 + s * 128 + col] + sred[1 * 256 + s * 128 + col]
                + sred[2 * 256 + s * 128 + col] + sred[3 * 256 + s * 128 + col];
        atomicAdd(&stats[s * 128 + col], v);
    }
}

// ---------------- BN finalize ----------------

__global__ void finalize_kernel(float* stats, float invN) {
    int c = threadIdx.x;
    float mean = stats[c] * invN;
    float var = stats[128 + c] * invN - mean * mean;
    stats[c] = mean;
    stats[128 + c] = rsqrtf(var + 1e-5f);
}

// ---------------- final normalize + relu -> d_out ----------------

__global__ __launch_bounds__(256) void outnorm_kernel(const float* __restrict__ agg,
                                                      const float* __restrict__ stats,
                                                      float* __restrict__ out, long total4) {
    long idx = (long)blockIdx.x * 256 + threadIdx.x;
    if (idx >= total4) return;
    int c0 = (int)((idx & 31) * 4);
    float4 v = ((const float4*)agg)[idx];
    float4 o;
    o.x = fmaxf((v.x - stats[c0 + 0]) * stats[128 + c0 + 0], 0.f);
    o.y = fmaxf((v.y - stats[c0 + 1]) * stats[128 + c0 + 1], 0.f);
    o.z = fmaxf((v.z - stats[c0 + 2]) * stats[128 + c0 + 2], 0.f);
    o.w = fmaxf((v.w - stats[c0 + 3]) * stats[128 + c0 + 3], 0.f);
    ((float4*)out)[idx] = o;
}

// ---------------- launch ----------------

extern "C" void kernel_launch(void* const* d_in, const int* in_sizes, int n_in,
                              void* d_out, int out_size, void* d_ws, size_t ws_size,
                              hipStream_t stream) {
    const float* x = (const float*)d_in[0];
    const int* ei = (const int*)d_in[1];
    int N = in_sizes[0] / DD;
    int E = in_sizes[1] / 2;
    const float* Wp[5];
    const float* bp[5];
    for (int l = 0; l < 5; l++) {
        Wp[l] = (const float*)d_in[2 + 2 * l];
        bp[l] = (const float*)d_in[3 + 2 * l];
    }

    char* ws = (char*)d_ws;
    size_t off = 0;
    auto alloc = [&](size_t bytes) -> char* {
        char* p = ws + off;
        off = (off + bytes + 511) & ~(size_t)511;
        return p;
    };
    int* cnt = (int*)alloc((size_t)N * 4);
    int* row_off = (int*)alloc(((size_t)N + 1) * 4);
    int* cursor = (int*)alloc((size_t)N * 4);
    int* partials = (int*)alloc(4096 * 4);
    float* inv_deg = (float*)alloc((size_t)N * 4);
    float* stats = (float*)alloc(5 * 256 * 4);
    unsigned short* whl = (unsigned short*)alloc(5 * 32768 * 2);
    int* csr = (int*)alloc((size_t)E * 4);
    unsigned short* hb = (unsigned short*)alloc((size_t)N * DD * 2);  // bf16 activations
    float* Sbuf = (float*)alloc((size_t)N * DD * 4);                  // fp32 gather output
    (void)ws_size;

    const int* srcv = ei;
    const int* dstv = ei + E;

    hipMemsetAsync(cnt, 0, (size_t)N * 4, stream);
    hipMemsetAsync(stats, 0, 5 * 256 * 4, stream);

    wsplit_kernel<<<5 * 16384 / 256, 256, 0, stream>>>(Wp[0], Wp[1], Wp[2], Wp[3], Wp[4], whl);

    long total4 = (long)N * (DD / 4);
    tobf16_kernel<<<(int)((total4 + 255) / 256), 256, 0, stream>>>(x, hb, total4);

    int psize = (N + NPART - 1) / NPART;
    hist_kernel<<<NPART * 128, 256, 0, stream>>>(dstv, cnt, E, psize);
    int nb = (N + 1023) / 1024;
    scanA_kernel<<<nb, 256, 0, stream>>>(cnt, row_off, partials, N);
    scanB_kernel<<<1, 256, 0, stream>>>(partials, nb);
    scanC_kernel<<<nb, 256, 0, stream>>>(cnt, row_off, cursor, inv_deg, partials, N);
    scatter_kernel<<<NPART * 128, 256, 0, stream>>>(srcv, dstv, cursor, csr, E, psize);

    float invN = 1.0f / (float)N;
    int gblocks = (N + 3) / 4;
    int mblocks = (N + 127) / 128;

    for (int l = 0; l < 5; l++) {
        if (l == 0) {
            gather_kernel<0><<<gblocks, 256, 0, stream>>>((const unsigned int*)hb, row_off, csr,
                                                          nullptr, Sbuf, N);
        } else {
            gather_kernel<1><<<gblocks, 256, 0, stream>>>((const unsigned int*)hb, row_off, csr,
                                                          stats + (l - 1) * 256, Sbuf, N);
        }
        if (l < 4) {
            mgemm_kernel<0><<<mblocks, 256, 0, stream>>>(Sbuf, hb, nullptr, whl + l * 32768,
                                                         bp[l], inv_deg, stats + l * 256, N);
        } else {
            mgemm_kernel<1><<<mblocks, 256, 0, stream>>>(Sbuf, nullptr, Sbuf, whl + l * 32768,
                                                         bp[l], inv_deg, stats + l * 256, N);
        }
        finalize_kernel<<<1, 128, 0, stream>>>(stats + l * 256, invN);
    }

    outnorm_kernel<<<(int)((total4 + 255) / 256), 256, 0, stream>>>(Sbuf, stats + 4 * 256,
                                                                    (float*)d_out, total4);
}

// Round 4
// 1006.608 us; speedup vs baseline: 1.4744x; 1.0082x over previous
//
#include <hip/hip_runtime.h>
#include <hip/hip_bf16.h>

#define DD 128
#define NPART 8

typedef __bf16 bf16x8 __attribute__((ext_vector_type(8)));
typedef float f32x4 __attribute__((ext_vector_type(4)));

__device__ inline unsigned short f2bf_rne(float f) {
    unsigned u = __float_as_uint(f);
    u += 0x7fff + ((u >> 16) & 1);
    return (unsigned short)(u >> 16);
}

// ---------------- CSR build ----------------

__global__ __launch_bounds__(256) void hist_kernel(const int* __restrict__ dst,
                                                   int* __restrict__ cnt, int E, int psize) {
    int part = blockIdx.x & (NPART - 1);
    int lo = part * psize, hi = lo + psize;
    int stride = (gridDim.x >> 3) * 256;
    for (int e = (blockIdx.x >> 3) * 256 + threadIdx.x; e < E; e += stride) {
        int d = dst[e];
        if (d >= lo && d < hi) atomicAdd(&cnt[d], 1);
    }
}

__global__ void scanA_kernel(const int* __restrict__ cnt, int* __restrict__ row_off,
                             int* __restrict__ partials, int N) {
    __shared__ int ls[256];
    int tid = threadIdx.x;
    int i = blockIdx.x * 1024 + tid * 4;
    int c0 = (i + 0 < N) ? cnt[i + 0] : 0;
    int c1 = (i + 1 < N) ? cnt[i + 1] : 0;
    int c2 = (i + 2 < N) ? cnt[i + 2] : 0;
    int c3 = (i + 3 < N) ? cnt[i + 3] : 0;
    int tot = c0 + c1 + c2 + c3;
    ls[tid] = tot;
    __syncthreads();
    for (int off = 1; off < 256; off <<= 1) {
        int v = (tid >= off) ? ls[tid - off] : 0;
        __syncthreads();
        ls[tid] += v;
        __syncthreads();
    }
    int excl = ls[tid] - tot;
    if (tid == 255) partials[blockIdx.x] = ls[255];
    int e0 = excl, e1 = e0 + c0, e2 = e1 + c1, e3 = e2 + c2;
    if (i + 0 < N) row_off[i + 0] = e0;
    if (i + 1 < N) row_off[i + 1] = e1;
    if (i + 2 < N) row_off[i + 2] = e2;
    if (i + 3 < N) row_off[i + 3] = e3;
}

__global__ __launch_bounds__(256) void scanB_kernel(int* partials, int nb) {
    __shared__ int ls[256];
    int tid = threadIdx.x;
    int base = 0;
    for (int c = 0; c < nb; c += 256) {
        int v = (c + tid < nb) ? partials[c + tid] : 0;
        ls[tid] = v;
        __syncthreads();
        for (int off = 1; off < 256; off <<= 1) {
            int t = (tid >= off) ? ls[tid - off] : 0;
            __syncthreads();
            ls[tid] += t;
            __syncthreads();
        }
        if (c + tid < nb) partials[c + tid] = ls[tid] - v + base;
        int tot = ls[255];
        __syncthreads();
        base += tot;
    }
}

__global__ void scanC_kernel(const int* __restrict__ cnt, int* __restrict__ row_off,
                             int* __restrict__ cursor, float* __restrict__ inv_deg,
                             const int* __restrict__ partials, int N) {
    int tid = threadIdx.x;
    int i = blockIdx.x * 1024 + tid * 4;
    int add = partials[blockIdx.x];
#pragma unroll
    for (int m = 0; m < 4; m++) {
        int idx = i + m;
        if (idx < N) {
            int v = row_off[idx] + add;
            row_off[idx] = v;
            cursor[idx] = v;
            int c = cnt[idx];
            inv_deg[idx] = 1.0f / (float)(c + 1);
            if (idx == N - 1) row_off[N] = v + c;
        }
    }
}

__global__ __launch_bounds__(256) void scatter_kernel(const int* __restrict__ src,
                                                      const int* __restrict__ dst,
                                                      int* __restrict__ cursor,
                                                      int* __restrict__ csr, int E, int psize) {
    int part = blockIdx.x & (NPART - 1);
    int lo = part * psize, hi = lo + psize;
    int stride = (gridDim.x >> 3) * 256;
    for (int e = (blockIdx.x >> 3) * 256 + threadIdx.x; e < E; e += stride) {
        int d = dst[e];
        if (d >= lo && d < hi) {
            int pos = atomicAdd(&cursor[d], 1);
            csr[pos] = src[e];
        }
    }
}

// ---------------- x -> bf16 ----------------

__global__ __launch_bounds__(256) void tobf16_kernel(const float* __restrict__ x,
                                                     unsigned short* __restrict__ h, long total4) {
    long idx = (long)blockIdx.x * 256 + threadIdx.x;
    if (idx >= total4) return;
    float4 v = ((const float4*)x)[idx];
    ushort4 o;
    o.x = f2bf_rne(v.x); o.y = f2bf_rne(v.y); o.z = f2bf_rne(v.z); o.w = f2bf_rne(v.w);
    ((ushort4*)h)[idx] = o;
}

// ---------------- gather (bf16 in, bf16 out, fused prev-layer BN+ReLU) ----------------
// one wave per node; lane owns 2 columns (one packed uint = 2 bf16).
// NORM=1: stats_raw holds raw (sum, sumsq); mean/rsqrt computed in prologue.

template <int NORM>
__global__ __launch_bounds__(256) void gather_kernel(const unsigned int* __restrict__ prev,
                                                     const int* __restrict__ row_off,
                                                     const int* __restrict__ csr,
                                                     const float* __restrict__ stats_raw,
                                                     float invN,
                                                     unsigned int* __restrict__ outp, int N) {
    int node = blockIdx.x * 4 + (threadIdx.x >> 6);
    if (node >= N) return;
    int lane = threadIdx.x & 63;
    float m0 = 0.f, m1 = 0.f, r0 = 1.f, r1 = 1.f;
    if (NORM) {
        int c = 2 * lane;
        float s0 = stats_raw[c], s1 = stats_raw[c + 1];
        float q0 = stats_raw[128 + c], q1 = stats_raw[129 + c];
        m0 = s0 * invN; m1 = s1 * invN;
        r0 = rsqrtf(q0 * invN - m0 * m0 + 1e-5f);
        r1 = rsqrtf(q1 * invN - m1 * m1 + 1e-5f);
    }
    int base = node * 64 + lane;
    float ax, ay;
    {
        unsigned u = prev[base];
        float vx = __uint_as_float(u << 16);
        float vy = __uint_as_float(u & 0xffff0000u);
        if (NORM) { ax = fmaxf((vx - m0) * r0, 0.f); ay = fmaxf((vy - m1) * r1, 0.f); }
        else      { ax = vx; ay = vy; }
    }
    int e = row_off[node], end = row_off[node + 1];
    for (; e + 8 <= end; e += 8) {
        int i0 = csr[e], i1 = csr[e + 1], i2 = csr[e + 2], i3 = csr[e + 3];
        int i4 = csr[e + 4], i5 = csr[e + 5], i6 = csr[e + 6], i7 = csr[e + 7];
        unsigned u0 = prev[i0 * 64 + lane];
        unsigned u1 = prev[i1 * 64 + lane];
        unsigned u2 = prev[i2 * 64 + lane];
        unsigned u3 = prev[i3 * 64 + lane];
        unsigned u4 = prev[i4 * 64 + lane];
        unsigned u5 = prev[i5 * 64 + lane];
        unsigned u6 = prev[i6 * 64 + lane];
        unsigned u7 = prev[i7 * 64 + lane];
#define GX(u) __uint_as_float((u) << 16)
#define GY(u) __uint_as_float((u) & 0xffff0000u)
        if (NORM) {
            ax += fmaxf((GX(u0) - m0) * r0, 0.f) + fmaxf((GX(u1) - m0) * r0, 0.f)
                + fmaxf((GX(u2) - m0) * r0, 0.f) + fmaxf((GX(u3) - m0) * r0, 0.f)
                + fmaxf((GX(u4) - m0) * r0, 0.f) + fmaxf((GX(u5) - m0) * r0, 0.f)
                + fmaxf((GX(u6) - m0) * r0, 0.f) + fmaxf((GX(u7) - m0) * r0, 0.f);
            ay += fmaxf((GY(u0) - m1) * r1, 0.f) + fmaxf((GY(u1) - m1) * r1, 0.f)
                + fmaxf((GY(u2) - m1) * r1, 0.f) + fmaxf((GY(u3) - m1) * r1, 0.f)
                + fmaxf((GY(u4) - m1) * r1, 0.f) + fmaxf((GY(u5) - m1) * r1, 0.f)
                + fmaxf((GY(u6) - m1) * r1, 0.f) + fmaxf((GY(u7) - m1) * r1, 0.f);
        } else {
            ax += GX(u0) + GX(u1) + GX(u2) + GX(u3) + GX(u4) + GX(u5) + GX(u6) + GX(u7);
            ay += GY(u0) + GY(u1) + GY(u2) + GY(u3) + GY(u4) + GY(u5) + GY(u6) + GY(u7);
        }
    }
    for (; e < end; e++) {
        unsigned u0 = prev[csr[e] * 64 + lane];
        if (NORM) { ax += fmaxf((GX(u0) - m0) * r0, 0.f); ay += fmaxf((GY(u0) - m1) * r1, 0.f); }
        else      { ax += GX(u0); ay += GY(u0); }
    }
#undef GX
#undef GY
    outp[base] = ((unsigned)f2bf_rne(ay) << 16) | (unsigned)f2bf_rne(ax);
}

// ---------------- W split into bf16 hi/lo planes ----------------

__global__ void wsplit_kernel(const float* __restrict__ W0, const float* __restrict__ W1,
                              const float* __restrict__ W2, const float* __restrict__ W3,
                              const float* __restrict__ W4, unsigned short* __restrict__ whl) {
    int idx = blockIdx.x * 256 + threadIdx.x;  // < 5*16384
    int l = idx >> 14, r = idx & 16383;
    const float* W = (l == 0) ? W0 : (l == 1) ? W1 : (l == 2) ? W2 : (l == 3) ? W3 : W4;
    float x = W[r];
    unsigned u = __float_as_uint(x);
    unsigned short h = (unsigned short)(u >> 16);
    float hf = __uint_as_float(u & 0xffff0000u);
    float lo = x - hf;  // exact
    unsigned short lw = (unsigned short)(__float_as_uint(lo) >> 16);
    whl[l * 32768 + r] = h;
    whl[l * 32768 + 16384 + r] = lw;
}

// ---------------- MFMA GEMM ----------------
// raw_agg = (Sh @ W^T) * inv_deg[row] + b[col]; 2-term split-bf16 (W hi/lo);
// writes raw agg as packed bf16 to hb; accumulates raw BN stats via atomics.

__global__ __launch_bounds__(256) void mgemm_kernel(const unsigned short* __restrict__ Sh,
                                                    unsigned short* __restrict__ hb,
                                                    const unsigned short* __restrict__ Whl,
                                                    const float* __restrict__ bias,
                                                    const float* __restrict__ inv_deg,
                                                    float* __restrict__ stats, int N) {
    __shared__ unsigned short ShL[128 * 128];  // XOR-swizzled 16B chunks
    const int t = threadIdx.x;
    const int i0 = blockIdx.x * 128;

    // stage S tile: 128 rows x 16 chunks of 8 bf16
#pragma unroll
    for (int b = 0; b < 8; b++) {
        int f = b * 256 + t;
        int r = f >> 4, k8 = f & 15;
        int row = i0 + r;
        uint4 v = make_uint4(0u, 0u, 0u, 0u);
        if (row < N) v = *(const uint4*)&Sh[(size_t)row * 128 + k8 * 8];
        *(uint4*)(ShL + r * 128 + ((k8 ^ (r & 7)) * 8)) = v;
    }
    __syncthreads();

    const int w = t >> 6, l = t & 63;
    const int ll = l & 15, lh = l >> 4;
    const unsigned short* Wh = Whl;
    const unsigned short* Wl2 = Whl + 16384;
    f32x4 acc[2][8];
#pragma unroll
    for (int st = 0; st < 2; st++)
#pragma unroll
        for (int jt = 0; jt < 8; jt++) acc[st][jt] = (f32x4){0.f, 0.f, 0.f, 0.f};

    const int r0 = w * 32 + ll;
    const int r1 = r0 + 16;
#pragma unroll
    for (int ks = 0; ks < 4; ks++) {
        int k8 = ks * 4 + lh;
        bf16x8 ah0 = *(const bf16x8*)(ShL + r0 * 128 + ((k8 ^ (r0 & 7)) * 8));
        bf16x8 ah1 = *(const bf16x8*)(ShL + r1 * 128 + ((k8 ^ (r1 & 7)) * 8));
        int wk = ks * 32 + lh * 8;
#pragma unroll
        for (int jt = 0; jt < 8; jt++) {
            int wrow = jt * 16 + ll;
            bf16x8 bh = *(const bf16x8*)(Wh + wrow * 128 + wk);
            bf16x8 bl = *(const bf16x8*)(Wl2 + wrow * 128 + wk);
            acc[0][jt] = __builtin_amdgcn_mfma_f32_16x16x32_bf16(ah0, bh, acc[0][jt], 0, 0, 0);
            acc[1][jt] = __builtin_amdgcn_mfma_f32_16x16x32_bf16(ah1, bh, acc[1][jt], 0, 0, 0);
            acc[0][jt] = __builtin_amdgcn_mfma_f32_16x16x32_bf16(ah0, bl, acc[0][jt], 0, 0, 0);
            acc[1][jt] = __builtin_amdgcn_mfma_f32_16x16x32_bf16(ah1, bl, acc[1][jt], 0, 0, 0);
        }
    }

    float bj[8];
#pragma unroll
    for (int jt = 0; jt < 8; jt++) bj[jt] = bias[jt * 16 + ll];
    float cs[8], cq[8];
#pragma unroll
    for (int jt = 0; jt < 8; jt++) { cs[jt] = 0.f; cq[jt] = 0.f; }
#pragma unroll
    for (int st = 0; st < 2; st++) {
#pragma unroll
        for (int reg = 0; reg < 4; reg++) {
            int row = i0 + w * 32 + st * 16 + lh * 4 + reg;
            bool valid = row < N;
            float sc = valid ? inv_deg[row] : 0.f;
#pragma unroll
            for (int jt = 0; jt < 8; jt++) {
                float o = acc[st][jt][reg] * sc + bj[jt];
                if (valid) {
                    hb[(size_t)row * 128 + jt * 16 + ll] = f2bf_rne(o);
                    cs[jt] += o;
                    cq[jt] += o * o;
                }
            }
        }
    }
#pragma unroll
    for (int jt = 0; jt < 8; jt++) {
        cs[jt] += __shfl_xor(cs[jt], 16);
        cs[jt] += __shfl_xor(cs[jt], 32);
        cq[jt] += __shfl_xor(cq[jt], 16);
        cq[jt] += __shfl_xor(cq[jt], 32);
    }
    __syncthreads();  // all LDS reads done; reuse ShL for stats reduction
    float* sred = (float*)ShL;  // [4 waves][2 stats][128 cols]
    if (l < 16) {
#pragma unroll
        for (int jt = 0; jt < 8; jt++) {
            sred[w * 256 + jt * 16 + l] = cs[jt];
            sred[w * 256 + 128 + jt * 16 + l] = cq[jt];
        }
    }
    __syncthreads();
    {
        int col = t & 127, s = t >> 7;
        float v = sred[0 * 256 + s * 128 + col] + sred[1 * 256 + s * 128 + col]
                + sred[2 * 256 + s * 128 + col] + sred[3 * 256 + s * 128 + col];
        atomicAdd(&stats[s * 128 + col], v);
    }
}

// ---------------- final normalize + relu: bf16 raw agg -> fp32 d_out ----------------

__global__ __launch_bounds__(256) void outnorm_kernel(const unsigned int* __restrict__ hb,
                                                      const float* __restrict__ stats_raw,
                                                      float invN,
                                                      float2* __restrict__ out, int total) {
    __shared__ float mls[128], rls[128];
    int t = threadIdx.x;
    if (t < 128) {
        float mean = stats_raw[t] * invN;
        float var = stats_raw[128 + t] * invN - mean * mean;
        mls[t] = mean;
        rls[t] = rsqrtf(var + 1e-5f);
    }
    __syncthreads();
    int stride = gridDim.x * 256;
    for (int idx = blockIdx.x * 256 + t; idx < total; idx += stride) {
        int c = (idx & 63) * 2;
        unsigned u = hb[idx];
        float x = __uint_as_float(u << 16);
        float y = __uint_as_float(u & 0xffff0000u);
        float2 o;
        o.x = fmaxf((x - mls[c]) * rls[c], 0.f);
        o.y = fmaxf((y - mls[c + 1]) * rls[c + 1], 0.f);
        out[idx] = o;
    }
}

// ---------------- launch ----------------

extern "C" void kernel_launch(void* const* d_in, const int* in_sizes, int n_in,
                              void* d_out, int out_size, void* d_ws, size_t ws_size,
                              hipStream_t stream) {
    const float* x = (const float*)d_in[0];
    const int* ei = (const int*)d_in[1];
    int N = in_sizes[0] / DD;
    int E = in_sizes[1] / 2;
    const float* Wp[5];
    const float* bp[5];
    for (int l = 0; l < 5; l++) {
        Wp[l] = (const float*)d_in[2 + 2 * l];
        bp[l] = (const float*)d_in[3 + 2 * l];
    }

    char* ws = (char*)d_ws;
    size_t off = 0;
    auto alloc = [&](size_t bytes) -> char* {
        char* p = ws + off;
        off = (off + bytes + 511) & ~(size_t)511;
        return p;
    };
    int* cnt = (int*)alloc((size_t)N * 4);
    int* row_off = (int*)alloc(((size_t)N + 1) * 4);
    int* cursor = (int*)alloc((size_t)N * 4);
    int* partials = (int*)alloc(4096 * 4);
    float* inv_deg = (float*)alloc((size_t)N * 4);
    float* stats = (float*)alloc(5 * 256 * 4);
    unsigned short* whl = (unsigned short*)alloc(5 * 32768 * 2);
    int* csr = (int*)alloc((size_t)E * 4);
    unsigned short* hb = (unsigned short*)alloc((size_t)N * DD * 2);  // activations / raw agg (bf16)
    unsigned short* Sh = (unsigned short*)alloc((size_t)N * DD * 2);  // gather output (bf16)
    (void)ws_size;

    const int* srcv = ei;
    const int* dstv = ei + E;

    hipMemsetAsync(cnt, 0, (size_t)N * 4, stream);
    hipMemsetAsync(stats, 0, 5 * 256 * 4, stream);

    wsplit_kernel<<<5 * 16384 / 256, 256, 0, stream>>>(Wp[0], Wp[1], Wp[2], Wp[3], Wp[4], whl);

    long total4 = (long)N * (DD / 4);
    tobf16_kernel<<<(int)((total4 + 255) / 256), 256, 0, stream>>>(x, hb, total4);

    int psize = (N + NPART - 1) / NPART;
    hist_kernel<<<NPART * 256, 256, 0, stream>>>(dstv, cnt, E, psize);
    int nb = (N + 1023) / 1024;
    scanA_kernel<<<nb, 256, 0, stream>>>(cnt, row_off, partials, N);
    scanB_kernel<<<1, 256, 0, stream>>>(partials, nb);
    scanC_kernel<<<nb, 256, 0, stream>>>(cnt, row_off, cursor, inv_deg, partials, N);
    scatter_kernel<<<NPART * 256, 256, 0, stream>>>(srcv, dstv, cursor, csr, E, psize);

    float invN = 1.0f / (float)N;
    int gblocks = (N + 3) / 4;
    int mblocks = (N + 127) / 128;

    for (int l = 0; l < 5; l++) {
        if (l == 0) {
            gather_kernel<0><<<gblocks, 256, 0, stream>>>((const unsigned int*)hb, row_off, csr,
                                                          nullptr, invN, (unsigned int*)Sh, N);
        } else {
            gather_kernel<1><<<gblocks, 256, 0, stream>>>((const unsigned int*)hb, row_off, csr,
                                                          stats + (l - 1) * 256, invN,
                                                          (unsigned int*)Sh, N);
        }
        mgemm_kernel<<<mblocks, 256, 0, stream>>>(Sh, hb, whl + l * 32768, bp[l], inv_deg,
                                                  stats + l * 256, N);
    }

    int totalU = N * 64;
    outnorm_kernel<<<2048, 256, 0, stream>>>((const unsigned int*)hb, stats + 4 * 256, invN,
                                             (float2*)d_out, totalU);
}

// Round 5
// 845.994 us; speedup vs baseline: 1.7543x; 1.1899x over previous
//
#include <hip/hip_runtime.h>
#include <hip/hip_bf16.h>

#define DD 128
#define NPART 8

typedef __bf16 bf16x8 __attribute__((ext_vector_type(8)));
typedef float f32x4 __attribute__((ext_vector_type(4)));

__device__ inline unsigned short f2bf_rne(float f) {
    unsigned u = __float_as_uint(f);
    u += 0x7fff + ((u >> 16) & 1);
    return (unsigned short)(u >> 16);
}

// ---------------- CSR build ----------------

__global__ __launch_bounds__(256) void hist_kernel(const int* __restrict__ dst,
                                                   int* __restrict__ cnt, int E, int psize) {
    int part = blockIdx.x & (NPART - 1);
    int lo = part * psize, hi = lo + psize;
    int stride = (gridDim.x >> 3) * 256;
    for (int e = (blockIdx.x >> 3) * 256 + threadIdx.x; e < E; e += stride) {
        int d = dst[e];
        if (d >= lo && d < hi) atomicAdd(&cnt[d], 1);
    }
}

__global__ void scanA_kernel(const int* __restrict__ cnt, int* __restrict__ row_off,
                             int* __restrict__ partials, int N) {
    __shared__ int ls[256];
    int tid = threadIdx.x;
    int i = blockIdx.x * 1024 + tid * 4;
    int c0 = (i + 0 < N) ? cnt[i + 0] : 0;
    int c1 = (i + 1 < N) ? cnt[i + 1] : 0;
    int c2 = (i + 2 < N) ? cnt[i + 2] : 0;
    int c3 = (i + 3 < N) ? cnt[i + 3] : 0;
    int tot = c0 + c1 + c2 + c3;
    ls[tid] = tot;
    __syncthreads();
    for (int off = 1; off < 256; off <<= 1) {
        int v = (tid >= off) ? ls[tid - off] : 0;
        __syncthreads();
        ls[tid] += v;
        __syncthreads();
    }
    int excl = ls[tid] - tot;
    if (tid == 255) partials[blockIdx.x] = ls[255];
    int e0 = excl, e1 = e0 + c0, e2 = e1 + c1, e3 = e2 + c2;
    if (i + 0 < N) row_off[i + 0] = e0;
    if (i + 1 < N) row_off[i + 1] = e1;
    if (i + 2 < N) row_off[i + 2] = e2;
    if (i + 3 < N) row_off[i + 3] = e3;
}

__global__ __launch_bounds__(256) void scanB_kernel(int* partials, int nb) {
    __shared__ int ls[256];
    int tid = threadIdx.x;
    int base = 0;
    for (int c = 0; c < nb; c += 256) {
        int v = (c + tid < nb) ? partials[c + tid] : 0;
        ls[tid] = v;
        __syncthreads();
        for (int off = 1; off < 256; off <<= 1) {
            int t = (tid >= off) ? ls[tid - off] : 0;
            __syncthreads();
            ls[tid] += t;
            __syncthreads();
        }
        if (c + tid < nb) partials[c + tid] = ls[tid] - v + base;
        int tot = ls[255];
        __syncthreads();
        base += tot;
    }
}

__global__ void scanC_kernel(const int* __restrict__ cnt, int* __restrict__ row_off,
                             int* __restrict__ cursor, float* __restrict__ inv_deg,
                             const int* __restrict__ partials, int N) {
    int tid = threadIdx.x;
    int i = blockIdx.x * 1024 + tid * 4;
    int add = partials[blockIdx.x];
#pragma unroll
    for (int m = 0; m < 4; m++) {
        int idx = i + m;
        if (idx < N) {
            int v = row_off[idx] + add;
            row_off[idx] = v;
            cursor[idx] = v;
            int c = cnt[idx];
            inv_deg[idx] = 1.0f / (float)(c + 1);
            if (idx == N - 1) row_off[N] = v + c;
        }
    }
}

__global__ __launch_bounds__(256) void scatter_kernel(const int* __restrict__ src,
                                                      const int* __restrict__ dst,
                                                      int* __restrict__ cursor,
                                                      int* __restrict__ csr, int E, int psize) {
    int part = blockIdx.x & (NPART - 1);
    int lo = part * psize, hi = lo + psize;
    int stride = (gridDim.x >> 3) * 256;
    for (int e = (blockIdx.x >> 3) * 256 + threadIdx.x; e < E; e += stride) {
        int d = dst[e];
        if (d >= lo && d < hi) {
            int pos = atomicAdd(&cursor[d], 1);
            csr[pos] = src[e];
        }
    }
}

// ---------------- x -> bf16 ----------------

__global__ __launch_bounds__(256) void tobf16_kernel(const float* __restrict__ x,
                                                     unsigned short* __restrict__ h, long total4) {
    long idx = (long)blockIdx.x * 256 + threadIdx.x;
    if (idx >= total4) return;
    float4 v = ((const float4*)x)[idx];
    ushort4 o;
    o.x = f2bf_rne(v.x); o.y = f2bf_rne(v.y); o.z = f2bf_rne(v.z); o.w = f2bf_rne(v.w);
    ((ushort4*)h)[idx] = o;
}

// ---------------- gather: pure bf16 neighbor-sum + self, bf16 out ----------------
// one wave per node; 4 lane-groups of 16 handle 4 edges concurrently;
// each lane owns 8 columns (one uint4 = 16B). Cross-group shfl reduce at end.

#define ACC8(u)                                                         \
    do {                                                                \
        a[0] += __uint_as_float((u).x << 16);                           \
        a[1] += __uint_as_float((u).x & 0xffff0000u);                   \
        a[2] += __uint_as_float((u).y << 16);                           \
        a[3] += __uint_as_float((u).y & 0xffff0000u);                   \
        a[4] += __uint_as_float((u).z << 16);                           \
        a[5] += __uint_as_float((u).z & 0xffff0000u);                   \
        a[6] += __uint_as_float((u).w << 16);                           \
        a[7] += __uint_as_float((u).w & 0xffff0000u);                   \
    } while (0)

__global__ __launch_bounds__(256) void gather_kernel(const uint4* __restrict__ prev4,
                                                     const int* __restrict__ row_off,
                                                     const int* __restrict__ csr,
                                                     uint4* __restrict__ out4, int N) {
    int node = blockIdx.x * 4 + (threadIdx.x >> 6);
    if (node >= N) return;
    int lane = threadIdx.x & 63;
    int g = lane >> 4, c = lane & 15;
    float a[8];
#pragma unroll
    for (int j = 0; j < 8; j++) a[j] = 0.f;
    int e = row_off[node], end = row_off[node + 1];
    for (; e + 8 <= end; e += 8) {
        int ia = csr[e + g];
        int ib = csr[e + 4 + g];
        uint4 ua = prev4[ia * 16 + c];
        uint4 ub = prev4[ib * 16 + c];
        ACC8(ua);
        ACC8(ub);
    }
    if (e + 4 <= end) {
        int ia = csr[e + g];
        uint4 ua = prev4[ia * 16 + c];
        ACC8(ua);
        e += 4;
    }
    {
        int rem = end - e;
        if (g < rem) {
            int ia = csr[e + g];
            uint4 ua = prev4[ia * 16 + c];
            ACC8(ua);
        }
    }
#pragma unroll
    for (int j = 0; j < 8; j++) {
        a[j] += __shfl_xor(a[j], 16);
        a[j] += __shfl_xor(a[j], 32);
    }
    if (g == 0) {
        uint4 us = prev4[node * 16 + c];
        ACC8(us);  // self-loop message
        uint4 o;
        o.x = ((unsigned)f2bf_rne(a[1]) << 16) | f2bf_rne(a[0]);
        o.y = ((unsigned)f2bf_rne(a[3]) << 16) | f2bf_rne(a[2]);
        o.z = ((unsigned)f2bf_rne(a[5]) << 16) | f2bf_rne(a[4]);
        o.w = ((unsigned)f2bf_rne(a[7]) << 16) | f2bf_rne(a[6]);
        out4[node * 16 + c] = o;
    }
}

// ---------------- W split into bf16 hi/lo planes ----------------

__global__ void wsplit_kernel(const float* __restrict__ W0, const float* __restrict__ W1,
                              const float* __restrict__ W2, const float* __restrict__ W3,
                              const float* __restrict__ W4, unsigned short* __restrict__ whl) {
    int idx = blockIdx.x * 256 + threadIdx.x;  // < 5*16384
    int l = idx >> 14, r = idx & 16383;
    const float* W = (l == 0) ? W0 : (l == 1) ? W1 : (l == 2) ? W2 : (l == 3) ? W3 : W4;
    float x = W[r];
    unsigned u = __float_as_uint(x);
    unsigned short h = (unsigned short)(u >> 16);
    float hf = __uint_as_float(u & 0xffff0000u);
    float lo = x - hf;  // exact
    unsigned short lw = (unsigned short)(__float_as_uint(lo) >> 16);
    whl[l * 32768 + r] = h;
    whl[l * 32768 + 16384 + r] = lw;
}

// ---------------- MFMA GEMM ----------------
// raw_agg = (Sg @ W^T) * inv_deg[row] + b[col]; 2-term split-bf16 (W hi/lo).
// W plane staged in LDS (hi phase, then lo phase) -> inner loop is pure LDS+MFMA.
// Writes raw agg as packed bf16; accumulates raw BN stats via atomics.

__global__ __launch_bounds__(256) void mgemm_kernel(const unsigned short* __restrict__ Sg,
                                                    unsigned short* __restrict__ hb,
                                                    const unsigned short* __restrict__ Whl,
                                                    const float* __restrict__ bias,
                                                    const float* __restrict__ inv_deg,
                                                    float* __restrict__ stats, int N) {
    __shared__ unsigned short SL[128 * 128];  // S tile, XOR-swizzled 16B chunks
    __shared__ unsigned short WL[128 * 128];  // W plane (hi, then lo), same swizzle
    const int t = threadIdx.x;
    const int i0 = blockIdx.x * 128;

    // stage S tile + Wh plane
#pragma unroll
    for (int b = 0; b < 8; b++) {
        int f = b * 256 + t;
        int r = f >> 4, k8 = f & 15;
        int row = i0 + r;
        uint4 v = make_uint4(0u, 0u, 0u, 0u);
        if (row < N) v = *(const uint4*)&Sg[(size_t)row * 128 + k8 * 8];
        int lbase = r * 128 + ((k8 ^ (r & 7)) * 8);
        *(uint4*)(SL + lbase) = v;
        uint4 wv = *(const uint4*)&Whl[f * 8];
        *(uint4*)(WL + lbase) = wv;
    }
    __syncthreads();

    const int w = t >> 6, l = t & 63;
    const int ll = l & 15, lh = l >> 4;
    const int r0 = w * 32 + ll, r1 = r0 + 16;

    // A-fragments to registers (reused in both phases)
    bf16x8 a0[4], a1[4];
#pragma unroll
    for (int ks = 0; ks < 4; ks++) {
        int k8 = ks * 4 + lh;
        a0[ks] = *(const bf16x8*)(SL + r0 * 128 + ((k8 ^ (r0 & 7)) * 8));
        a1[ks] = *(const bf16x8*)(SL + r1 * 128 + ((k8 ^ (r1 & 7)) * 8));
    }

    f32x4 acc[2][8];
#pragma unroll
    for (int st = 0; st < 2; st++)
#pragma unroll
        for (int jt = 0; jt < 8; jt++) acc[st][jt] = (f32x4){0.f, 0.f, 0.f, 0.f};

    // hi phase
#pragma unroll
    for (int ks = 0; ks < 4; ks++) {
        int k8 = ks * 4 + lh;
#pragma unroll
        for (int jt = 0; jt < 8; jt++) {
            int wrow = jt * 16 + ll;
            bf16x8 bh = *(const bf16x8*)(WL + wrow * 128 + ((k8 ^ (wrow & 7)) * 8));
            acc[0][jt] = __builtin_amdgcn_mfma_f32_16x16x32_bf16(a0[ks], bh, acc[0][jt], 0, 0, 0);
            acc[1][jt] = __builtin_amdgcn_mfma_f32_16x16x32_bf16(a1[ks], bh, acc[1][jt], 0, 0, 0);
        }
    }
    __syncthreads();
    // stage Wl plane
#pragma unroll
    for (int b = 0; b < 8; b++) {
        int f = b * 256 + t;
        int r = f >> 4, k8 = f & 15;
        uint4 wv = *(const uint4*)&Whl[16384 + f * 8];
        *(uint4*)(WL + r * 128 + ((k8 ^ (r & 7)) * 8)) = wv;
    }
    __syncthreads();
    // lo phase
#pragma unroll
    for (int ks = 0; ks < 4; ks++) {
        int k8 = ks * 4 + lh;
#pragma unroll
        for (int jt = 0; jt < 8; jt++) {
            int wrow = jt * 16 + ll;
            bf16x8 bl = *(const bf16x8*)(WL + wrow * 128 + ((k8 ^ (wrow & 7)) * 8));
            acc[0][jt] = __builtin_amdgcn_mfma_f32_16x16x32_bf16(a0[ks], bl, acc[0][jt], 0, 0, 0);
            acc[1][jt] = __builtin_amdgcn_mfma_f32_16x16x32_bf16(a1[ks], bl, acc[1][jt], 0, 0, 0);
        }
    }

    // epilogue: scale + bias, store bf16, accumulate column stats
    float bj[8];
#pragma unroll
    for (int jt = 0; jt < 8; jt++) bj[jt] = bias[jt * 16 + ll];
    float cs[8], cq[8];
#pragma unroll
    for (int jt = 0; jt < 8; jt++) { cs[jt] = 0.f; cq[jt] = 0.f; }
#pragma unroll
    for (int st = 0; st < 2; st++) {
#pragma unroll
        for (int reg = 0; reg < 4; reg++) {
            int row = i0 + w * 32 + st * 16 + lh * 4 + reg;
            bool valid = row < N;
            float sc = valid ? inv_deg[row] : 0.f;
#pragma unroll
            for (int jt = 0; jt < 8; jt++) {
                float o = acc[st][jt][reg] * sc + bj[jt];
                if (valid) {
                    hb[(size_t)row * 128 + jt * 16 + ll] = f2bf_rne(o);
                    cs[jt] += o;
                    cq[jt] += o * o;
                }
            }
        }
    }
#pragma unroll
    for (int jt = 0; jt < 8; jt++) {
        cs[jt] += __shfl_xor(cs[jt], 16);
        cs[jt] += __shfl_xor(cs[jt], 32);
        cq[jt] += __shfl_xor(cq[jt], 16);
        cq[jt] += __shfl_xor(cq[jt], 32);
    }
    __syncthreads();  // all LDS reads done; reuse SL for stats reduction
    float* sred = (float*)SL;  // [4 waves][2 stats][128 cols]
    if (l < 16) {
#pragma unroll
        for (int jt = 0; jt < 8; jt++) {
            sred[w * 256 + jt * 16 + l] = cs[jt];
            sred[w * 256 + 128 + jt * 16 + l] = cq[jt];
        }
    }
    __syncthreads();
    {
        int col = t & 127, s = t >> 7;
        float v = sred[0 * 256 + s * 128 + col] + sred[1 * 256 + s * 128 + col]
                + sred[2 * 256 + s * 128 + col] + sred[3 * 256 + s * 128 + col];
        atomicAdd(&stats[s * 128 + col], v);
    }
}

// ---------------- per-node BN normalize + ReLU (bf16 -> bf16) ----------------

__global__ __launch_bounds__(256) void norm_kernel(const uint4* __restrict__ hb4,
                                                   const float* __restrict__ stats_raw,
                                                   float invN,
                                                   uint4* __restrict__ hn4, int totalQ) {
    __shared__ float mls[128], rls[128];
    int t = threadIdx.x;
    if (t < 128) {
        float mean = stats_raw[t] * invN;
        float var = stats_raw[128 + t] * invN - mean * mean;
        mls[t] = mean;
        rls[t] = rsqrtf(var + 1e-5f);
    }
    __syncthreads();
    int stride = gridDim.x * 256;
    for (int idx = blockIdx.x * 256 + t; idx < totalQ; idx += stride) {
        int c0 = (idx & 15) * 8;
        uint4 u = hb4[idx];
        float v[8];
        v[0] = __uint_as_float(u.x << 16); v[1] = __uint_as_float(u.x & 0xffff0000u);
        v[2] = __uint_as_float(u.y << 16); v[3] = __uint_as_float(u.y & 0xffff0000u);
        v[4] = __uint_as_float(u.z << 16); v[5] = __uint_as_float(u.z & 0xffff0000u);
        v[6] = __uint_as_float(u.w << 16); v[7] = __uint_as_float(u.w & 0xffff0000u);
#pragma unroll
        for (int j = 0; j < 8; j++) v[j] = fmaxf((v[j] - mls[c0 + j]) * rls[c0 + j], 0.f);
        uint4 o;
        o.x = ((unsigned)f2bf_rne(v[1]) << 16) | f2bf_rne(v[0]);
        o.y = ((unsigned)f2bf_rne(v[3]) << 16) | f2bf_rne(v[2]);
        o.z = ((unsigned)f2bf_rne(v[5]) << 16) | f2bf_rne(v[4]);
        o.w = ((unsigned)f2bf_rne(v[7]) << 16) | f2bf_rne(v[6]);
        hn4[idx] = o;
    }
}

// ---------------- final normalize + relu: bf16 raw agg -> fp32 d_out ----------------

__global__ __launch_bounds__(256) void outnorm_kernel(const uint4* __restrict__ hb4,
                                                      const float* __restrict__ stats_raw,
                                                      float invN,
                                                      float4* __restrict__ out4, int totalQ) {
    __shared__ float mls[128], rls[128];
    int t = threadIdx.x;
    if (t < 128) {
        float mean = stats_raw[t] * invN;
        float var = stats_raw[128 + t] * invN - mean * mean;
        mls[t] = mean;
        rls[t] = rsqrtf(var + 1e-5f);
    }
    __syncthreads();
    int stride = gridDim.x * 256;
    for (int idx = blockIdx.x * 256 + t; idx < totalQ; idx += stride) {
        int c0 = (idx & 15) * 8;
        uint4 u = hb4[idx];
        float v[8];
        v[0] = __uint_as_float(u.x << 16); v[1] = __uint_as_float(u.x & 0xffff0000u);
        v[2] = __uint_as_float(u.y << 16); v[3] = __uint_as_float(u.y & 0xffff0000u);
        v[4] = __uint_as_float(u.z << 16); v[5] = __uint_as_float(u.z & 0xffff0000u);
        v[6] = __uint_as_float(u.w << 16); v[7] = __uint_as_float(u.w & 0xffff0000u);
#pragma unroll
        for (int j = 0; j < 8; j++) v[j] = fmaxf((v[j] - mls[c0 + j]) * rls[c0 + j], 0.f);
        float4 o0, o1;
        o0.x = v[0]; o0.y = v[1]; o0.z = v[2]; o0.w = v[3];
        o1.x = v[4]; o1.y = v[5]; o1.z = v[6]; o1.w = v[7];
        out4[idx * 2 + 0] = o0;
        out4[idx * 2 + 1] = o1;
    }
}

// ---------------- launch ----------------

extern "C" void kernel_launch(void* const* d_in, const int* in_sizes, int n_in,
                              void* d_out, int out_size, void* d_ws, size_t ws_size,
                              hipStream_t stream) {
    const float* x = (const float*)d_in[0];
    const int* ei = (const int*)d_in[1];
    int N = in_sizes[0] / DD;
    int E = in_sizes[1] / 2;
    const float* Wp[5];
    const float* bp[5];
    for (int l = 0; l < 5; l++) {
        Wp[l] = (const float*)d_in[2 + 2 * l];
        bp[l] = (const float*)d_in[3 + 2 * l];
    }

    char* ws = (char*)d_ws;
    size_t off = 0;
    auto alloc = [&](size_t bytes) -> char* {
        char* p = ws + off;
        off = (off + bytes + 511) & ~(size_t)511;
        return p;
    };
    int* cnt = (int*)alloc((size_t)N * 4);
    int* row_off = (int*)alloc(((size_t)N + 1) * 4);
    int* cursor = (int*)alloc((size_t)N * 4);
    int* partials = (int*)alloc(4096 * 4);
    float* inv_deg = (float*)alloc((size_t)N * 4);
    float* stats = (float*)alloc(5 * 256 * 4);
    unsigned short* whl = (unsigned short*)alloc(5 * 32768 * 2);
    int* csr = (int*)alloc((size_t)E * 4);
    unsigned short* hn = (unsigned short*)alloc((size_t)N * DD * 2);  // normalized input (bf16)
    unsigned short* Sg = (unsigned short*)alloc((size_t)N * DD * 2);  // gather output (bf16)
    unsigned short* hb = (unsigned short*)alloc((size_t)N * DD * 2);  // raw agg (bf16)
    (void)ws_size;

    const int* srcv = ei;
    const int* dstv = ei + E;

    hipMemsetAsync(cnt, 0, (size_t)N * 4, stream);
    hipMemsetAsync(stats, 0, 5 * 256 * 4, stream);

    wsplit_kernel<<<5 * 16384 / 256, 256, 0, stream>>>(Wp[0], Wp[1], Wp[2], Wp[3], Wp[4], whl);

    long total4 = (long)N * (DD / 4);
    tobf16_kernel<<<(int)((total4 + 255) / 256), 256, 0, stream>>>(x, hn, total4);

    int psize = (N + NPART - 1) / NPART;
    hist_kernel<<<NPART * 256, 256, 0, stream>>>(dstv, cnt, E, psize);
    int nb = (N + 1023) / 1024;
    scanA_kernel<<<nb, 256, 0, stream>>>(cnt, row_off, partials, N);
    scanB_kernel<<<1, 256, 0, stream>>>(partials, nb);
    scanC_kernel<<<nb, 256, 0, stream>>>(cnt, row_off, cursor, inv_deg, partials, N);
    scatter_kernel<<<NPART * 256, 256, 0, stream>>>(srcv, dstv, cursor, csr, E, psize);

    float invN = 1.0f / (float)N;
    int gblocks = (N + 3) / 4;
    int mblocks = (N + 127) / 128;
    int totalQ = N * 16;  // uint4 count

    for (int l = 0; l < 5; l++) {
        gather_kernel<<<gblocks, 256, 0, stream>>>((const uint4*)hn, row_off, csr,
                                                   (uint4*)Sg, N);
        mgemm_kernel<<<mblocks, 256, 0, stream>>>(Sg, hb, whl + l * 32768, bp[l], inv_deg,
                                                  stats + l * 256, N);
        if (l < 4) {
            norm_kernel<<<2048, 256, 0, stream>>>((const uint4*)hb, stats + l * 256, invN,
                                                  (uint4*)hn, totalQ);
        }
    }

    outnorm_kernel<<<2048, 256, 0, stream>>>((const uint4*)hb, stats + 4 * 256, invN,
                                             (float4*)d_out, totalQ);
}